// Round 15
// baseline (740.793 us; speedup 1.0000x reference)
//
#include <hip/hip_runtime.h>
#include <hip/hip_bf16.h>

#define NN 100000
#define NE 1600000
#define D  128
#define NBK 256            // fine dst-buckets
#define BPBF 391           // nodes per fine bucket (256*391 = 100096 >= NN)
#define SCAP 8192          // per-bucket LDS edge capacity (mean 6250, sigma 79)
#define EPB 2048           // edges per binning block

typedef unsigned short u16;
typedef unsigned int   u32;
typedef __attribute__((ext_vector_type(8))) _Float16 half8;
typedef __attribute__((ext_vector_type(4))) float f32x4;

__device__ __forceinline__ float b2f(u16 u){
  union { u32 i; float f; } v; v.i = ((u32)u) << 16; return v.f;
}
__device__ __forceinline__ u16 f2b(float f){
  union { float f; u32 i; } v; v.f = f;
  u32 r = v.i + 0x7fffu + ((v.i >> 16) & 1u);   // round-to-nearest-even
  return (u16)(r >> 16);
}
__device__ __forceinline__ u16 f2h(float f){
  union { _Float16 h; u16 u; } v; v.h = (_Float16)f; return v.u;
}

// ---------------- f32 -> f16 convert (weights) ----------------
__global__ void k_cvt16(const float* __restrict__ s, u16* __restrict__ d, int n4){
  int i = blockIdx.x * 256 + threadIdx.x;
  if (i >= n4) return;
  float4 v = ((const float4*)s)[i];
  ushort4 o;
  o.x = f2h(v.x); o.y = f2h(v.y); o.z = f2h(v.z); o.w = f2h(v.w);
  ((ushort4*)d)[i] = o;
}

// ---------------- CSR build ----------------
__global__ void k_count(const int* __restrict__ dst, int* __restrict__ cnt){
  int e = blockIdx.x * 256 + threadIdx.x;
  if (e < NE) atomicAdd(&cnt[dst[e]], 1);
}

__global__ __launch_bounds__(256) void k_scan1(const int* __restrict__ cnt,
                                               int* __restrict__ rp,
                                               int* __restrict__ partials){
  int i = blockIdx.x * 256 + threadIdx.x;
  int v = (i < NN) ? cnt[i] : 0;
  int lane = threadIdx.x & 63, w = threadIdx.x >> 6;
  int s = v;
  #pragma unroll
  for (int off = 1; off < 64; off <<= 1){
    int t = __shfl_up(s, off, 64);
    if (lane >= off) s += t;
  }
  __shared__ int wsum[4];
  if (lane == 63) wsum[w] = s;
  __syncthreads();
  int add = 0;
  #pragma unroll
  for (int k = 0; k < 4; ++k) if (k < w) add += wsum[k];
  s += add;
  if (i < NN) rp[i] = s - v;
  if (threadIdx.x == 255) partials[blockIdx.x] = s;
}

__global__ __launch_bounds__(512) void k_scan2(int* __restrict__ partials, int nb){
  int i = threadIdx.x;
  int v = (i < nb) ? partials[i] : 0;
  int lane = i & 63, w = i >> 6;
  int s = v;
  #pragma unroll
  for (int off = 1; off < 64; off <<= 1){
    int t = __shfl_up(s, off, 64);
    if (lane >= off) s += t;
  }
  __shared__ int wsum[8];
  if (lane == 63) wsum[w] = s;
  __syncthreads();
  int add = 0;
  #pragma unroll
  for (int k = 0; k < 8; ++k) if (k < w) add += wsum[k];
  s += add;
  if (i < nb) partials[i] = s - v;
}

// finalize rp, init fine-bucket cursors, dinv
__global__ void k_scan3(int* __restrict__ rp, const int* __restrict__ partials,
                        const int* __restrict__ cnt,
                        int* __restrict__ bcur, float* __restrict__ dinv){
  int i = blockIdx.x * 256 + threadIdx.x;
  if (i < NN){
    int r = rp[i] + partials[blockIdx.x];
    rp[i] = r;
    if ((i % BPBF) == 0) bcur[i / BPBF] = r;
    dinv[i] = rsqrtf(1.0f + (float)cnt[i]);
  }
  if (i == 0) rp[NN] = NE;
}

// pass A: LDS-bin edges by fine dst bucket, write (dst,src) pairs bucket-grouped
__global__ __launch_bounds__(256) void k_fill2a(
    const int* __restrict__ src, const int* __restrict__ dst,
    int* __restrict__ bcur, uint2* __restrict__ pairs)
{
  __shared__ int bcnt[NBK], boff[NBK], bbase[NBK], bsave[NBK];
  __shared__ uint2 buf[EPB];
  const int tid = threadIdx.x;
  const int e0 = blockIdx.x * EPB + tid * 8;
  for (int b = tid; b < NBK; b += 256) bcnt[b] = 0;
  __syncthreads();
  int d[8], s[8], nval = 0;
  if (e0 + 8 <= NE){
    int4 d0 = *(const int4*)(dst + e0), d1 = *(const int4*)(dst + e0 + 4);
    int4 s0 = *(const int4*)(src + e0), s1 = *(const int4*)(src + e0 + 4);
    d[0]=d0.x; d[1]=d0.y; d[2]=d0.z; d[3]=d0.w;
    d[4]=d1.x; d[5]=d1.y; d[6]=d1.z; d[7]=d1.w;
    s[0]=s0.x; s[1]=s0.y; s[2]=s0.z; s[3]=s0.w;
    s[4]=s1.x; s[5]=s1.y; s[6]=s1.z; s[7]=s1.w;
    nval = 8;
  } else {
    for (int j = 0; j < 8; ++j){
      int e = e0 + j;
      if (e < NE){ d[j] = dst[e]; s[j] = src[e]; ++nval; }
    }
  }
  for (int j = 0; j < 8; ++j)
    if (j < nval) atomicAdd(&bcnt[d[j] / BPBF], 1);
  __syncthreads();
  if (tid == 0){
    int run = 0;
    #pragma unroll
    for (int b = 0; b < NBK; ++b){
      boff[b] = run; bsave[b] = bcnt[b]; run += bcnt[b]; bcnt[b] = 0;
    }
  }
  __syncthreads();
  if (tid < NBK) bbase[tid] = atomicAdd(&bcur[tid], bsave[tid]);
  for (int j = 0; j < 8; ++j)
    if (j < nval){
      int b = d[j] / BPBF;
      int p = boff[b] + atomicAdd(&bcnt[b], 1);
      buf[p] = make_uint2((u32)d[j], (u32)s[j]);
    }
  __syncthreads();
  int total = boff[NBK - 1] + bsave[NBK - 1];
  for (int i = tid; i < total; i += 256){
    uint2 pv = buf[i];
    int b = (int)pv.x / BPBF;
    pairs[bbase[b] + (i - boff[b])] = pv;
  }
}

// pass B: per-bucket LDS counting sort -> coalesced sorted write.
__global__ __launch_bounds__(256) void k_sortb(
    const uint2* __restrict__ pairs, const int* __restrict__ rp,
    int* __restrict__ sorted)
{
  __shared__ int cnt[BPBF + 1];
  __shared__ int srt[SCAP];
  __shared__ int wpart[4];
  const int b   = blockIdx.x;
  const int n0  = b * BPBF;
  int n1 = n0 + BPBF; if (n1 > NN) n1 = NN;
  if (n0 >= NN) return;
  const int nn  = n1 - n0;
  const int e0  = rp[n0];
  const int e1  = rp[n1];
  const int L   = e1 - e0;
  const int tid = threadIdx.x;
  for (int i = tid; i < nn; i += 256) cnt[i] = 0;
  __syncthreads();
  for (int i = tid; i < L; i += 256){
    uint2 p = pairs[e0 + i];
    atomicAdd(&cnt[(int)p.x - n0], 1);
  }
  __syncthreads();
  int i0 = tid * 2, i1 = tid * 2 + 1;
  int v0 = (i0 < nn) ? cnt[i0] : 0;
  int v1 = (i1 < nn) ? cnt[i1] : 0;
  int tsum = v0 + v1;
  int lane = tid & 63, w = tid >> 6;
  int s = tsum;
  #pragma unroll
  for (int off = 1; off < 64; off <<= 1){
    int t = __shfl_up(s, off, 64);
    if (lane >= off) s += t;
  }
  if (lane == 63) wpart[w] = s;
  __syncthreads();
  int add = 0;
  #pragma unroll
  for (int k = 0; k < 4; ++k) if (k < w) add += wpart[k];
  int excl = s - tsum + add;
  __syncthreads();
  if (i0 < nn) cnt[i0] = excl;
  if (i1 < nn) cnt[i1] = excl + v0;
  __syncthreads();
  for (int i = tid; i < L; i += 256){
    uint2 p = pairs[e0 + i];
    int pos = atomicAdd(&cnt[(int)p.x - n0], 1);
    if (pos < SCAP) srt[pos] = (int)p.y;
  }
  __syncthreads();
  for (int i = tid; i < L; i += 256)
    sorted[e0 + i] = srt[i];
}

// ---------------- MFMA GEMM: stage-once W, grid-stride tiles, A prefetch ----
// out[n][128] = A @ W^T.  A = KCH f16 chunks [NN][128]; A0F: chunk0 is f32.
// W f16 [128][KCH*128] staged swizzled into dynamic LDS (KCH*32KB) ONCE.
// Steady-state loop: prefetch A(t+grid) -> 32*KCH MFMA on t -> store t.
// mode A (dinv): g_out = bf16(h*dinv[row]); mode B: relu?(h+bias) -> f16/f32.
template<int KCH, int A0F>
__global__ __launch_bounds__(512, (KCH == 1 ? 4 : 2)) void k_mgemm(
    const u16* __restrict__ a0, const u16* __restrict__ a1, const u16* __restrict__ a2,
    const float* __restrict__ a0f,
    const u16* __restrict__ Wf,
    const float* __restrict__ dinv, u16* __restrict__ g_out,
    const float* __restrict__ bias, int relu, int out_f16,
    void* __restrict__ outp)
{
  extern __shared__ u16 Ws[];
  const int tid  = threadIdx.x;
  const int w    = tid >> 6, lane = tid & 63;
  const int c    = lane & 15, q = lane >> 4;
  const int swz  = (c & 7) << 4;
  const int wstride = KCH * D;
  const int tiles = (NN + 127) / 128;   // 782

  // stage all KCH chunks of W (swizzled rows)
  #pragma unroll
  for (int cc = 0; cc < KCH; ++cc){
    for (int idx = tid; idx < 2048; idx += 512){
      int o = idx >> 4, ks = (idx & 15) * 8;
      uint4 v = *(const uint4*)(Wf + o * wstride + cc * D + ks);
      *(uint4*)((char*)Ws + cc * 32768 + ((o * 256 + ks * 2) ^ ((o & 7) << 4))) = v;
    }
  }

  int t = blockIdx.x;
  if (t >= tiles) return;

  half8 cur[KCH][4], nxt[KCH][4];
  auto loadA = [&](int tt, half8 (&dst)[KCH][4]){
    int arow = tt * 128 + w * 16 + c; if (arow >= NN) arow = NN - 1;
    #pragma unroll
    for (int cc = 0; cc < KCH; ++cc){
      #pragma unroll
      for (int kk = 0; kk < 4; ++kk){
        if constexpr (A0F != 0){
          if (cc == 0){
            const float* p = a0f + arow * D + kk * 32 + q * 8;
            float4 v0 = *(const float4*)(p);
            float4 v1 = *(const float4*)(p + 4);
            dst[cc][kk][0] = (_Float16)v0.x; dst[cc][kk][1] = (_Float16)v0.y;
            dst[cc][kk][2] = (_Float16)v0.z; dst[cc][kk][3] = (_Float16)v0.w;
            dst[cc][kk][4] = (_Float16)v1.x; dst[cc][kk][5] = (_Float16)v1.y;
            dst[cc][kk][6] = (_Float16)v1.z; dst[cc][kk][7] = (_Float16)v1.w;
            continue;
          }
        }
        const u16* ach = (cc == 0) ? a0 : ((cc == 1) ? a1 : a2);
        dst[cc][kk] = *(const half8*)(ach + arow * D + kk * 32 + q * 8);
      }
    }
  };

  loadA(t, cur);           // overlaps with W staging (independent)
  __syncthreads();         // W visible

  while (true){
    int tn = t + (int)gridDim.x;
    if (tn < tiles) loadA(tn, nxt);

    f32x4 acc[8];
    #pragma unroll
    for (int f = 0; f < 8; ++f) acc[f] = (f32x4){0.f, 0.f, 0.f, 0.f};
    #pragma unroll
    for (int cc = 0; cc < KCH; ++cc)
      #pragma unroll
      for (int kk = 0; kk < 4; ++kk)
        #pragma unroll
        for (int f = 0; f < 8; ++f){
          const int lbyte = cc * 32768 + ((((f * 16 + c) * 256) + kk * 64 + q * 16) ^ swz);
          half8 bh = *(const half8*)((const char*)Ws + lbyte);
          acc[f] = __builtin_amdgcn_mfma_f32_16x16x32_f16(cur[cc][kk], bh, acc[f], 0, 0, 0);
        }

    const int rowbase = t * 128 + w * 16;
    if (dinv){
      #pragma unroll
      for (int i = 0; i < 4; ++i){
        int row = rowbase + q * 4 + i;
        if (row < NN){
          float di = dinv[row];
          #pragma unroll
          for (int f = 0; f < 8; ++f)
            g_out[row * D + f * 16 + c] = f2b(acc[f][i] * di);
        }
      }
    } else {
      #pragma unroll
      for (int i = 0; i < 4; ++i){
        int row = rowbase + q * 4 + i;
        if (row < NN){
          #pragma unroll
          for (int f = 0; f < 8; ++f){
            float o = acc[f][i] + bias[f * 16 + c];
            if (relu) o = fmaxf(o, 0.f);
            if (out_f16) ((u16*)outp)[row * D + f * 16 + c] = f2h(o);
            else         ((float*)outp)[row * D + f * 16 + c] = o;
          }
        }
      }
    }

    if (tn >= tiles) break;
    #pragma unroll
    for (int cc = 0; cc < KCH; ++cc)
      #pragma unroll
      for (int kk = 0; kk < 4; ++kk) cur[cc][kk] = nxt[cc][kk];
    t = tn;
  }
}

// ---------------- CSR aggregation (bf16 g in, f16 xs out) ----------------
__global__ __launch_bounds__(256) void k_aggr(
    const int* __restrict__ rp, const int* __restrict__ sorted,
    const uint2* __restrict__ g2, const float* __restrict__ dinv,
    const float* __restrict__ bias, u16* __restrict__ xs)
{
  int node = blockIdx.x * 4 + (threadIdx.x >> 6);
  int l = threadIdx.x & 63;
  int h = l >> 5, j = l & 31;
  int e0 = rp[node], e1 = rp[node + 1];
  float a0 = 0.f, a1 = 0.f, a2 = 0.f, a3 = 0.f;
  if (h == 0){
    uint2 sv = g2[node * 32 + j];
    a0 = b2f((u16)sv.x); a1 = b2f((u16)(sv.x >> 16));
    a2 = b2f((u16)sv.y); a3 = b2f((u16)(sv.y >> 16));
  }
  int e = e0 + h;
  for (; e + 6 < e1; e += 8){
    int s0 = sorted[e], s1 = sorted[e + 2], s2 = sorted[e + 4], s3 = sorted[e + 6];
    uint2 v0 = g2[s0 * 32 + j], v1 = g2[s1 * 32 + j];
    uint2 v2 = g2[s2 * 32 + j], v3 = g2[s3 * 32 + j];
    a0 += b2f((u16)v0.x) + b2f((u16)v1.x) + b2f((u16)v2.x) + b2f((u16)v3.x);
    a1 += b2f((u16)(v0.x >> 16)) + b2f((u16)(v1.x >> 16))
        + b2f((u16)(v2.x >> 16)) + b2f((u16)(v3.x >> 16));
    a2 += b2f((u16)v0.y) + b2f((u16)v1.y) + b2f((u16)v2.y) + b2f((u16)v3.y);
    a3 += b2f((u16)(v0.y >> 16)) + b2f((u16)(v1.y >> 16))
        + b2f((u16)(v2.y >> 16)) + b2f((u16)(v3.y >> 16));
  }
  for (; e < e1; e += 2){
    uint2 v = g2[sorted[e] * 32 + j];
    a0 += b2f((u16)v.x); a1 += b2f((u16)(v.x >> 16));
    a2 += b2f((u16)v.y); a3 += b2f((u16)(v.y >> 16));
  }
  a0 += __shfl(a0, l ^ 32, 64);
  a1 += __shfl(a1, l ^ 32, 64);
  a2 += __shfl(a2, l ^ 32, 64);
  a3 += __shfl(a3, l ^ 32, 64);
  if (h == 0){
    float dn = dinv[node];
    float o0 = fmaxf(fmaf(a0, dn, bias[4 * j + 0]), 0.f);
    float o1 = fmaxf(fmaf(a1, dn, bias[4 * j + 1]), 0.f);
    float o2 = fmaxf(fmaf(a2, dn, bias[4 * j + 2]), 0.f);
    float o3 = fmaxf(fmaf(a3, dn, bias[4 * j + 3]), 0.f);
    uint2 ov;
    ov.x = ((u32)f2h(o1) << 16) | (u32)f2h(o0);
    ov.y = ((u32)f2h(o3) << 16) | (u32)f2h(o2);
    ((uint2*)xs)[node * 32 + j] = ov;
  }
}

extern "C" void kernel_launch(void* const* d_in, const int* in_sizes, int n_in,
                              void* d_out, int out_size, void* d_ws, size_t ws_size,
                              hipStream_t stream)
{
  const float* x   = (const float*)d_in[0];
  const int*   ei  = (const int*)d_in[1];
  const float* W0  = (const float*)d_in[2];
  const float* b0  = (const float*)d_in[3];
  const float* W1  = (const float*)d_in[4];
  const float* b1  = (const float*)d_in[5];
  const float* W2  = (const float*)d_in[6];
  const float* b2  = (const float*)d_in[7];
  const float* Wp0 = (const float*)d_in[8];
  const float* bp0 = (const float*)d_in[9];
  const float* Wp1 = (const float*)d_in[10];
  const float* bp1 = (const float*)d_in[11];
  const int* src = ei;
  const int* dst = ei + NE;

  char* ws = (char*)d_ws;
  float* dinv    = (float*)(ws);                    // 400KB
  int*   cnt     = (int*)  (ws + (512u << 10));
  int*   rp      = (int*)  (ws + (1024u << 10));
  int*   partials= (int*)  (ws + (2048u << 10));    // 2KB
  int*   bcur    = (int*)  (ws + (2048u << 10) + 4096); // 1KB
  int*   sorted  = (int*)  (ws + (2560u << 10));    // 6.4MB, ends 8.9MB
  u16* W0f  = (u16*)(ws + 9437184u);
  u16* W1f  = W0f + 16384;
  u16* W2f  = W1f + 16384;
  u16* Wp0f = W2f + 16384;
  u16* Wp1f = Wp0f + 49152;
  uint2* pairs = (uint2*)(ws + (10240u << 10));     // 12.8MB, ends 22.8MB
  u16*  g    = (u16*)  (ws + (24576u << 10));       // 25.6MB (bf16), ends 49.6MB
  u16*  z1   = (u16*)  (ws + (51200u << 10));       // 25.6MB (f16), ends 75.6MB
  u16*  xs0  = (u16*)  (ws + (81920u << 10));       // 25.6MB each (f16)
  u16*  xs1  = xs0 + NN * D;
  u16*  xs2  = xs1 + NN * D;
  float* out = (float*)d_out;

  const int NB = (NN + 255) / 256;   // 391

  // weight conversions (tiny)
  k_cvt16<<<16, 256, 0, stream>>>(W0, W0f, 4096);
  k_cvt16<<<16, 256, 0, stream>>>(W1, W1f, 4096);
  k_cvt16<<<16, 256, 0, stream>>>(W2, W2f, 4096);
  k_cvt16<<<48, 256, 0, stream>>>(Wp0, Wp0f, 12288);
  k_cvt16<<<16, 256, 0, stream>>>(Wp1, Wp1f, 4096);

  // CSR build
  hipMemsetAsync(cnt, 0, NN * sizeof(int), stream);
  k_count<<<NE / 256, 256, 0, stream>>>(dst, cnt);
  k_scan1<<<NB, 256, 0, stream>>>(cnt, rp, partials);
  k_scan2<<<1, 512, 0, stream>>>(partials, NB);
  k_scan3<<<NB, 256, 0, stream>>>(rp, partials, cnt, bcur, dinv);
  k_fill2a<<<(NE + EPB - 1) / EPB, 256, 0, stream>>>(src, dst, bcur, pairs);
  k_sortb<<<NBK, 256, 0, stream>>>(pairs, rp, sorted);

  // layer 0: A = x (f32 -> f16 in-register)
  k_mgemm<1,1><<<512, 512, 32768, stream>>>(nullptr, nullptr, nullptr, x, W0f,
                                            dinv, g, nullptr, 0, 0, nullptr);
  k_aggr<<<NN / 4, 256, 0, stream>>>(rp, sorted, (const uint2*)g, dinv, b0, xs0);
  // layer 1
  k_mgemm<1,0><<<512, 512, 32768, stream>>>(xs0, nullptr, nullptr, nullptr, W1f,
                                            dinv, g, nullptr, 0, 0, nullptr);
  k_aggr<<<NN / 4, 256, 0, stream>>>(rp, sorted, (const uint2*)g, dinv, b1, xs1);
  // layer 2
  k_mgemm<1,0><<<512, 512, 32768, stream>>>(xs1, nullptr, nullptr, nullptr, W2f,
                                            dinv, g, nullptr, 0, 0, nullptr);
  k_aggr<<<NN / 4, 256, 0, stream>>>(rp, sorted, (const uint2*)g, dinv, b2, xs2);
  // projection: z1 = relu(hcat @ Wp0^T + bp0)  (f16 out, whole W in 96KB LDS)
  k_mgemm<3,0><<<256, 512, 98304, stream>>>(xs0, xs1, xs2, nullptr, Wp0f,
                                            nullptr, nullptr, bp0, 1, 1, z1);
  // out = z1 @ Wp1^T + bp1  (f32 out)
  k_mgemm<1,0><<<512, 512, 32768, stream>>>(z1, nullptr, nullptr, nullptr, Wp1f,
                                            nullptr, nullptr, bp1, 0, 0, out);
}

// Round 16
// 559.906 us; speedup vs baseline: 1.3231x; 1.3231x over previous
//
#include <hip/hip_runtime.h>
#include <hip/hip_bf16.h>

#define NN 100000
#define NE 1600000
#define D  128
#define NBK 256            // fine dst-buckets
#define BPBF 391           // nodes per fine bucket (256*391 = 100096 >= NN)
#define SCAP 8192          // per-bucket LDS edge capacity (mean 6250, sigma 79)
#define EPB 2048           // edges per binning block

typedef unsigned short u16;
typedef unsigned int   u32;
typedef __attribute__((ext_vector_type(8))) _Float16 half8;
typedef __attribute__((ext_vector_type(4))) float f32x4;

__device__ __forceinline__ float b2f(u16 u){
  union { u32 i; float f; } v; v.i = ((u32)u) << 16; return v.f;
}
__device__ __forceinline__ u16 f2b(float f){
  union { float f; u32 i; } v; v.f = f;
  u32 r = v.i + 0x7fffu + ((v.i >> 16) & 1u);   // round-to-nearest-even
  return (u16)(r >> 16);
}
__device__ __forceinline__ u16 f2h(float f){
  union { _Float16 h; u16 u; } v; v.h = (_Float16)f; return v.u;
}

// ---------------- f32 -> f16 convert (weights) ----------------
__global__ void k_cvt16(const float* __restrict__ s, u16* __restrict__ d, int n4){
  int i = blockIdx.x * 256 + threadIdx.x;
  if (i >= n4) return;
  float4 v = ((const float4*)s)[i];
  ushort4 o;
  o.x = f2h(v.x); o.y = f2h(v.y); o.z = f2h(v.z); o.w = f2h(v.w);
  ((ushort4*)d)[i] = o;
}

// ---------------- CSR build ----------------
__global__ void k_count(const int* __restrict__ dst, int* __restrict__ cnt){
  int e = blockIdx.x * 256 + threadIdx.x;
  if (e < NE) atomicAdd(&cnt[dst[e]], 1);
}

__global__ __launch_bounds__(256) void k_scan1(const int* __restrict__ cnt,
                                               int* __restrict__ rp,
                                               int* __restrict__ partials){
  int i = blockIdx.x * 256 + threadIdx.x;
  int v = (i < NN) ? cnt[i] : 0;
  int lane = threadIdx.x & 63, w = threadIdx.x >> 6;
  int s = v;
  #pragma unroll
  for (int off = 1; off < 64; off <<= 1){
    int t = __shfl_up(s, off, 64);
    if (lane >= off) s += t;
  }
  __shared__ int wsum[4];
  if (lane == 63) wsum[w] = s;
  __syncthreads();
  int add = 0;
  #pragma unroll
  for (int k = 0; k < 4; ++k) if (k < w) add += wsum[k];
  s += add;
  if (i < NN) rp[i] = s - v;
  if (threadIdx.x == 255) partials[blockIdx.x] = s;
}

__global__ __launch_bounds__(512) void k_scan2(int* __restrict__ partials, int nb){
  int i = threadIdx.x;
  int v = (i < nb) ? partials[i] : 0;
  int lane = i & 63, w = i >> 6;
  int s = v;
  #pragma unroll
  for (int off = 1; off < 64; off <<= 1){
    int t = __shfl_up(s, off, 64);
    if (lane >= off) s += t;
  }
  __shared__ int wsum[8];
  if (lane == 63) wsum[w] = s;
  __syncthreads();
  int add = 0;
  #pragma unroll
  for (int k = 0; k < 8; ++k) if (k < w) add += wsum[k];
  s += add;
  if (i < nb) partials[i] = s - v;
}

// finalize rp, init fine-bucket cursors, dinv
__global__ void k_scan3(int* __restrict__ rp, const int* __restrict__ partials,
                        const int* __restrict__ cnt,
                        int* __restrict__ bcur, float* __restrict__ dinv){
  int i = blockIdx.x * 256 + threadIdx.x;
  if (i < NN){
    int r = rp[i] + partials[blockIdx.x];
    rp[i] = r;
    if ((i % BPBF) == 0) bcur[i / BPBF] = r;
    dinv[i] = rsqrtf(1.0f + (float)cnt[i]);
  }
  if (i == 0) rp[NN] = NE;
}

// pass A: LDS-bin edges by fine dst bucket, write (dst,src) pairs bucket-grouped
__global__ __launch_bounds__(256) void k_fill2a(
    const int* __restrict__ src, const int* __restrict__ dst,
    int* __restrict__ bcur, uint2* __restrict__ pairs)
{
  __shared__ int bcnt[NBK], boff[NBK], bbase[NBK], bsave[NBK];
  __shared__ uint2 buf[EPB];
  const int tid = threadIdx.x;
  const int e0 = blockIdx.x * EPB + tid * 8;
  for (int b = tid; b < NBK; b += 256) bcnt[b] = 0;
  __syncthreads();
  int d[8], s[8], nval = 0;
  if (e0 + 8 <= NE){
    int4 d0 = *(const int4*)(dst + e0), d1 = *(const int4*)(dst + e0 + 4);
    int4 s0 = *(const int4*)(src + e0), s1 = *(const int4*)(src + e0 + 4);
    d[0]=d0.x; d[1]=d0.y; d[2]=d0.z; d[3]=d0.w;
    d[4]=d1.x; d[5]=d1.y; d[6]=d1.z; d[7]=d1.w;
    s[0]=s0.x; s[1]=s0.y; s[2]=s0.z; s[3]=s0.w;
    s[4]=s1.x; s[5]=s1.y; s[6]=s1.z; s[7]=s1.w;
    nval = 8;
  } else {
    for (int j = 0; j < 8; ++j){
      int e = e0 + j;
      if (e < NE){ d[j] = dst[e]; s[j] = src[e]; ++nval; }
    }
  }
  for (int j = 0; j < 8; ++j)
    if (j < nval) atomicAdd(&bcnt[d[j] / BPBF], 1);
  __syncthreads();
  if (tid == 0){
    int run = 0;
    #pragma unroll
    for (int b = 0; b < NBK; ++b){
      boff[b] = run; bsave[b] = bcnt[b]; run += bcnt[b]; bcnt[b] = 0;
    }
  }
  __syncthreads();
  if (tid < NBK) bbase[tid] = atomicAdd(&bcur[tid], bsave[tid]);
  for (int j = 0; j < 8; ++j)
    if (j < nval){
      int b = d[j] / BPBF;
      int p = boff[b] + atomicAdd(&bcnt[b], 1);
      buf[p] = make_uint2((u32)d[j], (u32)s[j]);
    }
  __syncthreads();
  int total = boff[NBK - 1] + bsave[NBK - 1];
  for (int i = tid; i < total; i += 256){
    uint2 pv = buf[i];
    int b = (int)pv.x / BPBF;
    pairs[bbase[b] + (i - boff[b])] = pv;
  }
}

// pass B: per-bucket LDS counting sort -> coalesced sorted write.
__global__ __launch_bounds__(256) void k_sortb(
    const uint2* __restrict__ pairs, const int* __restrict__ rp,
    int* __restrict__ sorted)
{
  __shared__ int cnt[BPBF + 1];
  __shared__ int srt[SCAP];
  __shared__ int wpart[4];
  const int b   = blockIdx.x;
  const int n0  = b * BPBF;
  int n1 = n0 + BPBF; if (n1 > NN) n1 = NN;
  if (n0 >= NN) return;
  const int nn  = n1 - n0;
  const int e0  = rp[n0];
  const int e1  = rp[n1];
  const int L   = e1 - e0;
  const int tid = threadIdx.x;
  for (int i = tid; i < nn; i += 256) cnt[i] = 0;
  __syncthreads();
  for (int i = tid; i < L; i += 256){
    uint2 p = pairs[e0 + i];
    atomicAdd(&cnt[(int)p.x - n0], 1);
  }
  __syncthreads();
  int i0 = tid * 2, i1 = tid * 2 + 1;
  int v0 = (i0 < nn) ? cnt[i0] : 0;
  int v1 = (i1 < nn) ? cnt[i1] : 0;
  int tsum = v0 + v1;
  int lane = tid & 63, w = tid >> 6;
  int s = tsum;
  #pragma unroll
  for (int off = 1; off < 64; off <<= 1){
    int t = __shfl_up(s, off, 64);
    if (lane >= off) s += t;
  }
  if (lane == 63) wpart[w] = s;
  __syncthreads();
  int add = 0;
  #pragma unroll
  for (int k = 0; k < 4; ++k) if (k < w) add += wpart[k];
  int excl = s - tsum + add;
  __syncthreads();
  if (i0 < nn) cnt[i0] = excl;
  if (i1 < nn) cnt[i1] = excl + v0;
  __syncthreads();
  for (int i = tid; i < L; i += 256){
    uint2 p = pairs[e0 + i];
    int pos = atomicAdd(&cnt[(int)p.x - n0], 1);
    if (pos < SCAP) srt[pos] = (int)p.y;
  }
  __syncthreads();
  for (int i = tid; i < L; i += 256)
    sorted[e0 + i] = srt[i];
}

// ---------------- MFMA GEMM (f16 W in 32KB LDS, 512 threads / 128 rows) -----
// Round-13 structure + A-load hoist: A fragments for chunk cc are loaded
// BEFORE the W staging + barrier (independent of LDS), hiding their latency.
__global__ __launch_bounds__(512, 6) void k_mgemm(
    const u16* __restrict__ a0, const u16* __restrict__ a1, const u16* __restrict__ a2,
    const float* __restrict__ a0f, int kch,
    const u16* __restrict__ Wf,
    const float* __restrict__ dinv, u16* __restrict__ g_out,
    const float* __restrict__ bias, int relu, int out_f16,
    void* __restrict__ outp)
{
  __shared__ u16 Ws[16384];   // 32KB, XOR-swizzled rows
  const int tid  = threadIdx.x;
  const int w    = tid >> 6, lane = tid & 63;
  const int c    = lane & 15, q = lane >> 4;
  const int rowbase = blockIdx.x * 128 + w * 16;
  const int wstride = kch * D;
  const int swz = (c & 7) << 4;

  int arow = rowbase + c;
  if (arow >= NN) arow = NN - 1;        // clamp; stores are predicated

  f32x4 acc[8];
  #pragma unroll
  for (int f = 0; f < 8; ++f) acc[f] = (f32x4){0.f, 0.f, 0.f, 0.f};

  for (int cc = 0; cc < kch; ++cc){
    // --- hoisted A loads (independent of LDS; overlap with stage+barrier) ---
    half8 ah0, ah1, ah2, ah3;
    {
      const int useF32 = (cc == 0) && (a0f != nullptr);
      if (useF32){
        const float* p = a0f + arow * D + q * 8;
        float4 v0 = *(const float4*)(p);       float4 v1 = *(const float4*)(p + 4);
        float4 v2 = *(const float4*)(p + 32);  float4 v3 = *(const float4*)(p + 36);
        float4 v4 = *(const float4*)(p + 64);  float4 v5 = *(const float4*)(p + 68);
        float4 v6 = *(const float4*)(p + 96);  float4 v7 = *(const float4*)(p + 100);
        ah0[0]=(_Float16)v0.x; ah0[1]=(_Float16)v0.y; ah0[2]=(_Float16)v0.z; ah0[3]=(_Float16)v0.w;
        ah0[4]=(_Float16)v1.x; ah0[5]=(_Float16)v1.y; ah0[6]=(_Float16)v1.z; ah0[7]=(_Float16)v1.w;
        ah1[0]=(_Float16)v2.x; ah1[1]=(_Float16)v2.y; ah1[2]=(_Float16)v2.z; ah1[3]=(_Float16)v2.w;
        ah1[4]=(_Float16)v3.x; ah1[5]=(_Float16)v3.y; ah1[6]=(_Float16)v3.z; ah1[7]=(_Float16)v3.w;
        ah2[0]=(_Float16)v4.x; ah2[1]=(_Float16)v4.y; ah2[2]=(_Float16)v4.z; ah2[3]=(_Float16)v4.w;
        ah2[4]=(_Float16)v5.x; ah2[5]=(_Float16)v5.y; ah2[6]=(_Float16)v5.z; ah2[7]=(_Float16)v5.w;
        ah3[0]=(_Float16)v6.x; ah3[1]=(_Float16)v6.y; ah3[2]=(_Float16)v6.z; ah3[3]=(_Float16)v6.w;
        ah3[4]=(_Float16)v7.x; ah3[5]=(_Float16)v7.y; ah3[6]=(_Float16)v7.z; ah3[7]=(_Float16)v7.w;
      } else {
        const u16* ach = (cc == 0) ? a0 : ((cc == 1) ? a1 : a2);
        const u16* p = ach + arow * D + q * 8;
        ah0 = *(const half8*)(p);
        ah1 = *(const half8*)(p + 32);
        ah2 = *(const half8*)(p + 64);
        ah3 = *(const half8*)(p + 96);
      }
    }

    if (cc) __syncthreads();            // protect Ws from previous chunk's readers
    for (int idx = tid; idx < 2048; idx += 512){
      int o = idx >> 4, ks = (idx & 15) * 8;
      uint4 v = *(const uint4*)(Wf + o * wstride + cc * D + ks);
      *(uint4*)((char*)Ws + ((o * 256 + ks * 2) ^ ((o & 7) << 4))) = v;
    }
    __syncthreads();

    #pragma unroll
    for (int kk = 0; kk < 4; ++kk){
      half8 ah = (kk == 0) ? ah0 : ((kk == 1) ? ah1 : ((kk == 2) ? ah2 : ah3));
      #pragma unroll
      for (int f = 0; f < 8; ++f){
        const int lrow = f * 16 + c;
        const int lbyte = (lrow * 256 + kk * 64 + q * 16) ^ swz;
        half8 bh = *(const half8*)((const char*)Ws + lbyte);
        acc[f] = __builtin_amdgcn_mfma_f32_16x16x32_f16(ah, bh, acc[f], 0, 0, 0);
      }
    }
  }

  if (dinv){
    #pragma unroll
    for (int i = 0; i < 4; ++i){
      int row = rowbase + q * 4 + i;
      if (row < NN){
        float di = dinv[row];
        #pragma unroll
        for (int f = 0; f < 8; ++f)
          g_out[row * D + f * 16 + c] = f2b(acc[f][i] * di);
      }
    }
  } else {
    float bv[8];
    #pragma unroll
    for (int f = 0; f < 8; ++f) bv[f] = bias[f * 16 + c];
    #pragma unroll
    for (int i = 0; i < 4; ++i){
      int row = rowbase + q * 4 + i;
      if (row < NN){
        #pragma unroll
        for (int f = 0; f < 8; ++f){
          float o = acc[f][i] + bv[f];
          if (relu) o = fmaxf(o, 0.f);
          if (out_f16) ((u16*)outp)[row * D + f * 16 + c] = f2h(o);
          else         ((float*)outp)[row * D + f * 16 + c] = o;
        }
      }
    }
  }
}

// ---------------- CSR aggregation (bf16 g in, f16 xs out) ----------------
__global__ __launch_bounds__(256) void k_aggr(
    const int* __restrict__ rp, const int* __restrict__ sorted,
    const uint2* __restrict__ g2, const float* __restrict__ dinv,
    const float* __restrict__ bias, u16* __restrict__ xs)
{
  int node = blockIdx.x * 4 + (threadIdx.x >> 6);
  int l = threadIdx.x & 63;
  int h = l >> 5, j = l & 31;
  int e0 = rp[node], e1 = rp[node + 1];
  float a0 = 0.f, a1 = 0.f, a2 = 0.f, a3 = 0.f;
  if (h == 0){
    uint2 sv = g2[node * 32 + j];
    a0 = b2f((u16)sv.x); a1 = b2f((u16)(sv.x >> 16));
    a2 = b2f((u16)sv.y); a3 = b2f((u16)(sv.y >> 16));
  }
  int e = e0 + h;
  for (; e + 6 < e1; e += 8){
    int s0 = sorted[e], s1 = sorted[e + 2], s2 = sorted[e + 4], s3 = sorted[e + 6];
    uint2 v0 = g2[s0 * 32 + j], v1 = g2[s1 * 32 + j];
    uint2 v2 = g2[s2 * 32 + j], v3 = g2[s3 * 32 + j];
    a0 += b2f((u16)v0.x) + b2f((u16)v1.x) + b2f((u16)v2.x) + b2f((u16)v3.x);
    a1 += b2f((u16)(v0.x >> 16)) + b2f((u16)(v1.x >> 16))
        + b2f((u16)(v2.x >> 16)) + b2f((u16)(v3.x >> 16));
    a2 += b2f((u16)v0.y) + b2f((u16)v1.y) + b2f((u16)v2.y) + b2f((u16)v3.y);
    a3 += b2f((u16)(v0.y >> 16)) + b2f((u16)(v1.y >> 16))
        + b2f((u16)(v2.y >> 16)) + b2f((u16)(v3.y >> 16));
  }
  for (; e < e1; e += 2){
    uint2 v = g2[sorted[e] * 32 + j];
    a0 += b2f((u16)v.x); a1 += b2f((u16)(v.x >> 16));
    a2 += b2f((u16)v.y); a3 += b2f((u16)(v.y >> 16));
  }
  a0 += __shfl(a0, l ^ 32, 64);
  a1 += __shfl(a1, l ^ 32, 64);
  a2 += __shfl(a2, l ^ 32, 64);
  a3 += __shfl(a3, l ^ 32, 64);
  if (h == 0){
    float dn = dinv[node];
    float o0 = fmaxf(fmaf(a0, dn, bias[4 * j + 0]), 0.f);
    float o1 = fmaxf(fmaf(a1, dn, bias[4 * j + 1]), 0.f);
    float o2 = fmaxf(fmaf(a2, dn, bias[4 * j + 2]), 0.f);
    float o3 = fmaxf(fmaf(a3, dn, bias[4 * j + 3]), 0.f);
    uint2 ov;
    ov.x = ((u32)f2h(o1) << 16) | (u32)f2h(o0);
    ov.y = ((u32)f2h(o3) << 16) | (u32)f2h(o2);
    ((uint2*)xs)[node * 32 + j] = ov;
  }
}

extern "C" void kernel_launch(void* const* d_in, const int* in_sizes, int n_in,
                              void* d_out, int out_size, void* d_ws, size_t ws_size,
                              hipStream_t stream)
{
  const float* x   = (const float*)d_in[0];
  const int*   ei  = (const int*)d_in[1];
  const float* W0  = (const float*)d_in[2];
  const float* b0  = (const float*)d_in[3];
  const float* W1  = (const float*)d_in[4];
  const float* b1  = (const float*)d_in[5];
  const float* W2  = (const float*)d_in[6];
  const float* b2  = (const float*)d_in[7];
  const float* Wp0 = (const float*)d_in[8];
  const float* bp0 = (const float*)d_in[9];
  const float* Wp1 = (const float*)d_in[10];
  const float* bp1 = (const float*)d_in[11];
  const int* src = ei;
  const int* dst = ei + NE;

  char* ws = (char*)d_ws;
  float* dinv    = (float*)(ws);                    // 400KB
  int*   cnt     = (int*)  (ws + (512u << 10));
  int*   rp      = (int*)  (ws + (1024u << 10));
  int*   partials= (int*)  (ws + (2048u << 10));    // 2KB
  int*   bcur    = (int*)  (ws + (2048u << 10) + 4096); // 1KB
  int*   sorted  = (int*)  (ws + (2560u << 10));    // 6.4MB, ends 8.9MB
  u16* W0f  = (u16*)(ws + 9437184u);
  u16* W1f  = W0f + 16384;
  u16* W2f  = W1f + 16384;
  u16* Wp0f = W2f + 16384;
  u16* Wp1f = Wp0f + 49152;
  uint2* pairs = (uint2*)(ws + (10240u << 10));     // 12.8MB, ends 22.8MB
  u16*  g    = (u16*)  (ws + (24576u << 10));       // 25.6MB (bf16), ends 49.6MB
  u16*  z1   = (u16*)  (ws + (51200u << 10));       // 25.6MB (f16), ends 75.6MB
  u16*  xs0  = (u16*)  (ws + (81920u << 10));       // 25.6MB each (f16)
  u16*  xs1  = xs0 + NN * D;
  u16*  xs2  = xs1 + NN * D;
  float* out = (float*)d_out;

  const int NB = (NN + 255) / 256;   // 391

  // weight conversions (tiny)
  k_cvt16<<<16, 256, 0, stream>>>(W0, W0f, 4096);
  k_cvt16<<<16, 256, 0, stream>>>(W1, W1f, 4096);
  k_cvt16<<<16, 256, 0, stream>>>(W2, W2f, 4096);
  k_cvt16<<<48, 256, 0, stream>>>(Wp0, Wp0f, 12288);
  k_cvt16<<<16, 256, 0, stream>>>(Wp1, Wp1f, 4096);

  // CSR build
  hipMemsetAsync(cnt, 0, NN * sizeof(int), stream);
  k_count<<<NE / 256, 256, 0, stream>>>(dst, cnt);
  k_scan1<<<NB, 256, 0, stream>>>(cnt, rp, partials);
  k_scan2<<<1, 512, 0, stream>>>(partials, NB);
  k_scan3<<<NB, 256, 0, stream>>>(rp, partials, cnt, bcur, dinv);
  k_fill2a<<<(NE + EPB - 1) / EPB, 256, 0, stream>>>(src, dst, bcur, pairs);
  k_sortb<<<NBK, 256, 0, stream>>>(pairs, rp, sorted);

  const int GB = (NN + 127) / 128;   // 782

  // layer 0: A = x (f32 -> f16 in-register)
  k_mgemm<<<GB, 512, 0, stream>>>(nullptr, nullptr, nullptr, x, 1, W0f,
                                  dinv, g, nullptr, 0, 0, nullptr);
  k_aggr<<<NN / 4, 256, 0, stream>>>(rp, sorted, (const uint2*)g, dinv, b0, xs0);
  // layer 1
  k_mgemm<<<GB, 512, 0, stream>>>(xs0, nullptr, nullptr, nullptr, 1, W1f,
                                  dinv, g, nullptr, 0, 0, nullptr);
  k_aggr<<<NN / 4, 256, 0, stream>>>(rp, sorted, (const uint2*)g, dinv, b1, xs1);
  // layer 2
  k_mgemm<<<GB, 512, 0, stream>>>(xs1, nullptr, nullptr, nullptr, 1, W2f,
                                  dinv, g, nullptr, 0, 0, nullptr);
  k_aggr<<<NN / 4, 256, 0, stream>>>(rp, sorted, (const uint2*)g, dinv, b2, xs2);
  // projection: z1 = relu(hcat @ Wp0^T + bp0)  (f16 out)
  k_mgemm<<<GB, 512, 0, stream>>>(xs0, xs1, xs2, nullptr, 3, Wp0f,
                                  nullptr, nullptr, bp0, 1, 1, z1);
  // out = z1 @ Wp1^T + bp1  (f32 out)
  k_mgemm<<<GB, 512, 0, stream>>>(z1, nullptr, nullptr, nullptr, 1, Wp1f,
                                  nullptr, nullptr, bp1, 0, 0, out);
}

// Round 17
// 458.190 us; speedup vs baseline: 1.6168x; 1.2220x over previous
//
#include <hip/hip_runtime.h>
#include <hip/hip_bf16.h>

#define NN 100000
#define NE 1600000
#define D  128
#define NBK 256            // fine dst-buckets
#define BPBF 391           // nodes per fine bucket (256*391 = 100096 >= NN)
#define SCAP 8192          // per-bucket LDS edge capacity (mean 6250, sigma 79)
#define EPB 2048           // edges per binning block

typedef unsigned short u16;
typedef unsigned int   u32;
typedef __attribute__((ext_vector_type(8))) _Float16 half8;
typedef __attribute__((ext_vector_type(4))) float f32x4;

__device__ __forceinline__ float b2f(u16 u){
  union { u32 i; float f; } v; v.i = ((u32)u) << 16; return v.f;
}
__device__ __forceinline__ u16 f2b(float f){
  union { float f; u32 i; } v; v.f = f;
  u32 r = v.i + 0x7fffu + ((v.i >> 16) & 1u);   // round-to-nearest-even
  return (u16)(r >> 16);
}
__device__ __forceinline__ u16 f2h(float f){
  union { _Float16 h; u16 u; } v; v.h = (_Float16)f; return v.u;
}

// ---------------- f32 -> f16 convert (weights) ----------------
__global__ void k_cvt16(const float* __restrict__ s, u16* __restrict__ d, int n4){
  int i = blockIdx.x * 256 + threadIdx.x;
  if (i >= n4) return;
  float4 v = ((const float4*)s)[i];
  ushort4 o;
  o.x = f2h(v.x); o.y = f2h(v.y); o.z = f2h(v.z); o.w = f2h(v.w);
  ((ushort4*)d)[i] = o;
}

// ---------------- CSR build ----------------
__global__ void k_count(const int* __restrict__ dst, int* __restrict__ cnt){
  int e = blockIdx.x * 256 + threadIdx.x;
  if (e < NE) atomicAdd(&cnt[dst[e]], 1);
}

__global__ __launch_bounds__(256) void k_scan1(const int* __restrict__ cnt,
                                               int* __restrict__ rp,
                                               int* __restrict__ partials){
  int i = blockIdx.x * 256 + threadIdx.x;
  int v = (i < NN) ? cnt[i] : 0;
  int lane = threadIdx.x & 63, w = threadIdx.x >> 6;
  int s = v;
  #pragma unroll
  for (int off = 1; off < 64; off <<= 1){
    int t = __shfl_up(s, off, 64);
    if (lane >= off) s += t;
  }
  __shared__ int wsum[4];
  if (lane == 63) wsum[w] = s;
  __syncthreads();
  int add = 0;
  #pragma unroll
  for (int k = 0; k < 4; ++k) if (k < w) add += wsum[k];
  s += add;
  if (i < NN) rp[i] = s - v;
  if (threadIdx.x == 255) partials[blockIdx.x] = s;
}

__global__ __launch_bounds__(512) void k_scan2(int* __restrict__ partials, int nb){
  int i = threadIdx.x;
  int v = (i < nb) ? partials[i] : 0;
  int lane = i & 63, w = i >> 6;
  int s = v;
  #pragma unroll
  for (int off = 1; off < 64; off <<= 1){
    int t = __shfl_up(s, off, 64);
    if (lane >= off) s += t;
  }
  __shared__ int wsum[8];
  if (lane == 63) wsum[w] = s;
  __syncthreads();
  int add = 0;
  #pragma unroll
  for (int k = 0; k < 8; ++k) if (k < w) add += wsum[k];
  s += add;
  if (i < nb) partials[i] = s - v;
}

// finalize rp, init fine-bucket cursors, dinv
__global__ void k_scan3(int* __restrict__ rp, const int* __restrict__ partials,
                        const int* __restrict__ cnt,
                        int* __restrict__ bcur, float* __restrict__ dinv){
  int i = blockIdx.x * 256 + threadIdx.x;
  if (i < NN){
    int r = rp[i] + partials[blockIdx.x];
    rp[i] = r;
    if ((i % BPBF) == 0) bcur[i / BPBF] = r;
    dinv[i] = rsqrtf(1.0f + (float)cnt[i]);
  }
  if (i == 0) rp[NN] = NE;
}

// pass A: LDS-bin edges by fine dst bucket, write (dst,src) pairs bucket-grouped
__global__ __launch_bounds__(256) void k_fill2a(
    const int* __restrict__ src, const int* __restrict__ dst,
    int* __restrict__ bcur, uint2* __restrict__ pairs)
{
  __shared__ int bcnt[NBK], boff[NBK], bbase[NBK], bsave[NBK];
  __shared__ uint2 buf[EPB];
  const int tid = threadIdx.x;
  const int e0 = blockIdx.x * EPB + tid * 8;
  for (int b = tid; b < NBK; b += 256) bcnt[b] = 0;
  __syncthreads();
  int d[8], s[8], nval = 0;
  if (e0 + 8 <= NE){
    int4 d0 = *(const int4*)(dst + e0), d1 = *(const int4*)(dst + e0 + 4);
    int4 s0 = *(const int4*)(src + e0), s1 = *(const int4*)(src + e0 + 4);
    d[0]=d0.x; d[1]=d0.y; d[2]=d0.z; d[3]=d0.w;
    d[4]=d1.x; d[5]=d1.y; d[6]=d1.z; d[7]=d1.w;
    s[0]=s0.x; s[1]=s0.y; s[2]=s0.z; s[3]=s0.w;
    s[4]=s1.x; s[5]=s1.y; s[6]=s1.z; s[7]=s1.w;
    nval = 8;
  } else {
    for (int j = 0; j < 8; ++j){
      int e = e0 + j;
      if (e < NE){ d[j] = dst[e]; s[j] = src[e]; ++nval; }
    }
  }
  for (int j = 0; j < 8; ++j)
    if (j < nval) atomicAdd(&bcnt[d[j] / BPBF], 1);
  __syncthreads();
  if (tid == 0){
    int run = 0;
    #pragma unroll
    for (int b = 0; b < NBK; ++b){
      boff[b] = run; bsave[b] = bcnt[b]; run += bcnt[b]; bcnt[b] = 0;
    }
  }
  __syncthreads();
  if (tid < NBK) bbase[tid] = atomicAdd(&bcur[tid], bsave[tid]);
  for (int j = 0; j < 8; ++j)
    if (j < nval){
      int b = d[j] / BPBF;
      int p = boff[b] + atomicAdd(&bcnt[b], 1);
      buf[p] = make_uint2((u32)d[j], (u32)s[j]);
    }
  __syncthreads();
  int total = boff[NBK - 1] + bsave[NBK - 1];
  for (int i = tid; i < total; i += 256){
    uint2 pv = buf[i];
    int b = (int)pv.x / BPBF;
    pairs[bbase[b] + (i - boff[b])] = pv;
  }
}

// pass B: per-bucket LDS counting sort -> coalesced sorted write.
__global__ __launch_bounds__(256) void k_sortb(
    const uint2* __restrict__ pairs, const int* __restrict__ rp,
    int* __restrict__ sorted)
{
  __shared__ int cnt[BPBF + 1];
  __shared__ int srt[SCAP];
  __shared__ int wpart[4];
  const int b   = blockIdx.x;
  const int n0  = b * BPBF;
  int n1 = n0 + BPBF; if (n1 > NN) n1 = NN;
  if (n0 >= NN) return;
  const int nn  = n1 - n0;
  const int e0  = rp[n0];
  const int e1  = rp[n1];
  const int L   = e1 - e0;
  const int tid = threadIdx.x;
  for (int i = tid; i < nn; i += 256) cnt[i] = 0;
  __syncthreads();
  for (int i = tid; i < L; i += 256){
    uint2 p = pairs[e0 + i];
    atomicAdd(&cnt[(int)p.x - n0], 1);
  }
  __syncthreads();
  int i0 = tid * 2, i1 = tid * 2 + 1;
  int v0 = (i0 < nn) ? cnt[i0] : 0;
  int v1 = (i1 < nn) ? cnt[i1] : 0;
  int tsum = v0 + v1;
  int lane = tid & 63, w = tid >> 6;
  int s = tsum;
  #pragma unroll
  for (int off = 1; off < 64; off <<= 1){
    int t = __shfl_up(s, off, 64);
    if (lane >= off) s += t;
  }
  if (lane == 63) wpart[w] = s;
  __syncthreads();
  int add = 0;
  #pragma unroll
  for (int k = 0; k < 4; ++k) if (k < w) add += wpart[k];
  int excl = s - tsum + add;
  __syncthreads();
  if (i0 < nn) cnt[i0] = excl;
  if (i1 < nn) cnt[i1] = excl + v0;
  __syncthreads();
  for (int i = tid; i < L; i += 256){
    uint2 p = pairs[e0 + i];
    int pos = atomicAdd(&cnt[(int)p.x - n0], 1);
    if (pos < SCAP) srt[pos] = (int)p.y;
  }
  __syncthreads();
  for (int i = tid; i < L; i += 256)
    sorted[e0 + i] = srt[i];
}

// ---------------- MFMA GEMM (f16 W in 32KB LDS, 512 threads / 128 rows) -----
// out[n][128] = A @ W^T.  A = up to 3 f16 chunks [NN][128] (concat on K);
// a0f (optional): chunk 0 is f32, converted to f16 in-register.
// Wf f16 [128][kch*128].
// mode A (dinv): g_out[row][col] = bf16(h*dinv[row])
// mode B: out = optional_relu(h + bias) -> f16 or f32 per out_f16.
__global__ __launch_bounds__(512, 6) void k_mgemm(
    const u16* __restrict__ a0, const u16* __restrict__ a1, const u16* __restrict__ a2,
    const float* __restrict__ a0f, int kch,
    const u16* __restrict__ Wf,
    const float* __restrict__ dinv, u16* __restrict__ g_out,
    const float* __restrict__ bias, int relu, int out_f16,
    void* __restrict__ outp)
{
  __shared__ u16 Ws[16384];   // 32KB, XOR-swizzled rows
  const int tid  = threadIdx.x;
  const int w    = tid >> 6, lane = tid & 63;
  const int c    = lane & 15, q = lane >> 4;
  const int rowbase = blockIdx.x * 128 + w * 16;
  const int wstride = kch * D;
  const int swz = (c & 7) << 4;

  int arow = rowbase + c;
  if (arow >= NN) arow = NN - 1;        // clamp; stores are predicated

  f32x4 acc[8];
  #pragma unroll
  for (int f = 0; f < 8; ++f) acc[f] = (f32x4){0.f, 0.f, 0.f, 0.f};

  for (int cc = 0; cc < kch; ++cc){
    if (cc) __syncthreads();
    for (int idx = tid; idx < 2048; idx += 512){
      int o = idx >> 4, ks = (idx & 15) * 8;
      uint4 v = *(const uint4*)(Wf + o * wstride + cc * D + ks);
      *(uint4*)((char*)Ws + ((o * 256 + ks * 2) ^ ((o & 7) << 4))) = v;
    }
    __syncthreads();

    const int useF32 = (cc == 0) && (a0f != nullptr);
    const u16* ach = (cc == 0) ? a0 : ((cc == 1) ? a1 : a2);
    #pragma unroll
    for (int kk = 0; kk < 4; ++kk){
      const int koff = kk * 32 + q * 8;
      half8 ah;
      if (useF32){
        float4 v0 = *(const float4*)(a0f + arow * D + koff);
        float4 v1 = *(const float4*)(a0f + arow * D + koff + 4);
        ah[0] = (_Float16)v0.x; ah[1] = (_Float16)v0.y;
        ah[2] = (_Float16)v0.z; ah[3] = (_Float16)v0.w;
        ah[4] = (_Float16)v1.x; ah[5] = (_Float16)v1.y;
        ah[6] = (_Float16)v1.z; ah[7] = (_Float16)v1.w;
      } else {
        ah = *(const half8*)(ach + arow * D + koff);
      }
      #pragma unroll
      for (int f = 0; f < 8; ++f){
        const int lrow = f * 16 + c;
        const int lbyte = (lrow * 256 + kk * 64 + q * 16) ^ swz;
        half8 bh = *(const half8*)((const char*)Ws + lbyte);
        acc[f] = __builtin_amdgcn_mfma_f32_16x16x32_f16(ah, bh, acc[f], 0, 0, 0);
      }
    }
  }

  if (dinv){
    #pragma unroll
    for (int i = 0; i < 4; ++i){
      int row = rowbase + q * 4 + i;
      if (row < NN){
        float di = dinv[row];
        #pragma unroll
        for (int f = 0; f < 8; ++f)
          g_out[row * D + f * 16 + c] = f2b(acc[f][i] * di);
      }
    }
  } else {
    float bv[8];
    #pragma unroll
    for (int f = 0; f < 8; ++f) bv[f] = bias[f * 16 + c];
    #pragma unroll
    for (int i = 0; i < 4; ++i){
      int row = rowbase + q * 4 + i;
      if (row < NN){
        #pragma unroll
        for (int f = 0; f < 8; ++f){
          float o = acc[f][i] + bv[f];
          if (relu) o = fmaxf(o, 0.f);
          if (out_f16) ((u16*)outp)[row * D + f * 16 + c] = f2h(o);
          else         ((float*)outp)[row * D + f * 16 + c] = o;
        }
      }
    }
  }
}

// ---------------- CSR aggregation (bf16 g in, f16 xs out) ----------------
// wave per node, halves over even/odd edges; lane covers 4 features via uint2.
__global__ __launch_bounds__(256) void k_aggr(
    const int* __restrict__ rp, const int* __restrict__ sorted,
    const uint2* __restrict__ g2, const float* __restrict__ dinv,
    const float* __restrict__ bias, u16* __restrict__ xs)
{
  int node = blockIdx.x * 4 + (threadIdx.x >> 6);
  int l = threadIdx.x & 63;
  int h = l >> 5, j = l & 31;
  int e0 = rp[node], e1 = rp[node + 1];
  float a0 = 0.f, a1 = 0.f, a2 = 0.f, a3 = 0.f;
  if (h == 0){
    uint2 sv = g2[node * 32 + j];
    a0 = b2f((u16)sv.x); a1 = b2f((u16)(sv.x >> 16));
    a2 = b2f((u16)sv.y); a3 = b2f((u16)(sv.y >> 16));
  }
  int e = e0 + h;
  for (; e + 6 < e1; e += 8){
    int s0 = sorted[e], s1 = sorted[e + 2], s2 = sorted[e + 4], s3 = sorted[e + 6];
    uint2 v0 = g2[s0 * 32 + j], v1 = g2[s1 * 32 + j];
    uint2 v2 = g2[s2 * 32 + j], v3 = g2[s3 * 32 + j];
    a0 += b2f((u16)v0.x) + b2f((u16)v1.x) + b2f((u16)v2.x) + b2f((u16)v3.x);
    a1 += b2f((u16)(v0.x >> 16)) + b2f((u16)(v1.x >> 16))
        + b2f((u16)(v2.x >> 16)) + b2f((u16)(v3.x >> 16));
    a2 += b2f((u16)v0.y) + b2f((u16)v1.y) + b2f((u16)v2.y) + b2f((u16)v3.y);
    a3 += b2f((u16)(v0.y >> 16)) + b2f((u16)(v1.y >> 16))
        + b2f((u16)(v2.y >> 16)) + b2f((u16)(v3.y >> 16));
  }
  for (; e < e1; e += 2){
    uint2 v = g2[sorted[e] * 32 + j];
    a0 += b2f((u16)v.x); a1 += b2f((u16)(v.x >> 16));
    a2 += b2f((u16)v.y); a3 += b2f((u16)(v.y >> 16));
  }
  a0 += __shfl(a0, l ^ 32, 64);
  a1 += __shfl(a1, l ^ 32, 64);
  a2 += __shfl(a2, l ^ 32, 64);
  a3 += __shfl(a3, l ^ 32, 64);
  if (h == 0){
    float dn = dinv[node];
    float o0 = fmaxf(fmaf(a0, dn, bias[4 * j + 0]), 0.f);
    float o1 = fmaxf(fmaf(a1, dn, bias[4 * j + 1]), 0.f);
    float o2 = fmaxf(fmaf(a2, dn, bias[4 * j + 2]), 0.f);
    float o3 = fmaxf(fmaf(a3, dn, bias[4 * j + 3]), 0.f);
    uint2 ov;
    ov.x = ((u32)f2h(o1) << 16) | (u32)f2h(o0);
    ov.y = ((u32)f2h(o3) << 16) | (u32)f2h(o2);
    ((uint2*)xs)[node * 32 + j] = ov;
  }
}

extern "C" void kernel_launch(void* const* d_in, const int* in_sizes, int n_in,
                              void* d_out, int out_size, void* d_ws, size_t ws_size,
                              hipStream_t stream)
{
  const float* x   = (const float*)d_in[0];
  const int*   ei  = (const int*)d_in[1];
  const float* W0  = (const float*)d_in[2];
  const float* b0  = (const float*)d_in[3];
  const float* W1  = (const float*)d_in[4];
  const float* b1  = (const float*)d_in[5];
  const float* W2  = (const float*)d_in[6];
  const float* b2  = (const float*)d_in[7];
  const float* Wp0 = (const float*)d_in[8];
  const float* bp0 = (const float*)d_in[9];
  const float* Wp1 = (const float*)d_in[10];
  const float* bp1 = (const float*)d_in[11];
  const int* src = ei;
  const int* dst = ei + NE;

  char* ws = (char*)d_ws;
  float* dinv    = (float*)(ws);                    // 400KB
  int*   cnt     = (int*)  (ws + (512u << 10));
  int*   rp      = (int*)  (ws + (1024u << 10));
  int*   partials= (int*)  (ws + (2048u << 10));    // 2KB
  int*   bcur    = (int*)  (ws + (2048u << 10) + 4096); // 1KB
  int*   sorted  = (int*)  (ws + (2560u << 10));    // 6.4MB, ends 8.9MB
  u16* W0f  = (u16*)(ws + 9437184u);
  u16* W1f  = W0f + 16384;
  u16* W2f  = W1f + 16384;
  u16* Wp0f = W2f + 16384;
  u16* Wp1f = Wp0f + 49152;
  uint2* pairs = (uint2*)(ws + (10240u << 10));     // 12.8MB, ends 22.8MB
  u16*  g    = (u16*)  (ws + (24576u << 10));       // 25.6MB (bf16), ends 49.6MB
  u16*  z1   = (u16*)  (ws + (51200u << 10));       // 25.6MB (f16), ends 75.6MB
  u16*  xs0  = (u16*)  (ws + (81920u << 10));       // 25.6MB each (f16)
  u16*  xs1  = xs0 + NN * D;
  u16*  xs2  = xs1 + NN * D;
  float* out = (float*)d_out;

  const int NB = (NN + 255) / 256;   // 391

  // weight conversions (tiny)
  k_cvt16<<<16, 256, 0, stream>>>(W0, W0f, 4096);
  k_cvt16<<<16, 256, 0, stream>>>(W1, W1f, 4096);
  k_cvt16<<<16, 256, 0, stream>>>(W2, W2f, 4096);
  k_cvt16<<<48, 256, 0, stream>>>(Wp0, Wp0f, 12288);
  k_cvt16<<<16, 256, 0, stream>>>(Wp1, Wp1f, 4096);

  // CSR build
  hipMemsetAsync(cnt, 0, NN * sizeof(int), stream);
  k_count<<<NE / 256, 256, 0, stream>>>(dst, cnt);
  k_scan1<<<NB, 256, 0, stream>>>(cnt, rp, partials);
  k_scan2<<<1, 512, 0, stream>>>(partials, NB);
  k_scan3<<<NB, 256, 0, stream>>>(rp, partials, cnt, bcur, dinv);
  k_fill2a<<<(NE + EPB - 1) / EPB, 256, 0, stream>>>(src, dst, bcur, pairs);
  k_sortb<<<NBK, 256, 0, stream>>>(pairs, rp, sorted);

  const int GB = (NN + 127) / 128;   // 782

  // layer 0: A = x (f32 -> f16 in-register)
  k_mgemm<<<GB, 512, 0, stream>>>(nullptr, nullptr, nullptr, x, 1, W0f,
                                  dinv, g, nullptr, 0, 0, nullptr);
  k_aggr<<<NN / 4, 256, 0, stream>>>(rp, sorted, (const uint2*)g, dinv, b0, xs0);
  // layer 1
  k_mgemm<<<GB, 512, 0, stream>>>(xs0, nullptr, nullptr, nullptr, 1, W1f,
                                  dinv, g, nullptr, 0, 0, nullptr);
  k_aggr<<<NN / 4, 256, 0, stream>>>(rp, sorted, (const uint2*)g, dinv, b1, xs1);
  // layer 2
  k_mgemm<<<GB, 512, 0, stream>>>(xs1, nullptr, nullptr, nullptr, 1, W2f,
                                  dinv, g, nullptr, 0, 0, nullptr);
  k_aggr<<<NN / 4, 256, 0, stream>>>(rp, sorted, (const uint2*)g, dinv, b2, xs2);
  // projection: z1 = relu(hcat @ Wp0^T + bp0)  (f16 out)
  k_mgemm<<<GB, 512, 0, stream>>>(xs0, xs1, xs2, nullptr, 3, Wp0f,
                                  nullptr, nullptr, bp0, 1, 1, z1);
  // out = z1 @ Wp1^T + bp1  (f32 out)
  k_mgemm<<<GB, 512, 0, stream>>>(z1, nullptr, nullptr, nullptr, 1, Wp1f,
                                  nullptr, nullptr, bp1, 0, 0, out);
}